// Round 1
// baseline (86.699 us; speedup 1.0000x reference)
//
#include <hip/hip_runtime.h>
#include <math.h>

#define NB 128
#define NC 1000
#define NC4 250          // NC / 4 float4s per row (4000 bytes, 16B-aligned per row)
#define NT 800
#define LOG2E 1.4426950408889634f

// Workspace layout (d_ws): float m[NB]; float nc[NB]; int minj[NB];  (1536 B)

// ---------------------------------------------------------------------------
// Kernel A: per-row max, conf@t=1, target confidence nc; init minj = NT.
// 128 blocks x 256 threads (threads 0..249 each own one float4 of the row).
// ---------------------------------------------------------------------------
__global__ __launch_bounds__(256) void prep_kernel(const float* __restrict__ logits,
                                                   float* __restrict__ wm,
                                                   float* __restrict__ wnc,
                                                   int* __restrict__ wminj) {
    __shared__ float sred[4];
    __shared__ float sb;
    int r = blockIdx.x;
    int tid = threadIdx.x;
    const float4* row4 = (const float4*)(logits + r * NC);

    float4 v = make_float4(0.f, 0.f, 0.f, 0.f);
    bool act = tid < NC4;
    float mv = -INFINITY;
    if (act) {
        v = row4[tid];
        mv = fmaxf(fmaxf(v.x, v.y), fmaxf(v.z, v.w));
    }
    for (int o = 32; o > 0; o >>= 1) mv = fmaxf(mv, __shfl_xor(mv, o, 64));
    if ((tid & 63) == 0) sred[tid >> 6] = mv;
    __syncthreads();
    if (tid == 0) sb = fmaxf(fmaxf(sred[0], sred[1]), fmaxf(sred[2], sred[3]));
    __syncthreads();
    float m = sb;

    float s = 0.f;
    if (act) s = expf(v.x - m) + expf(v.y - m) + expf(v.z - m) + expf(v.w - m);
    for (int o = 32; o > 0; o >>= 1) s += __shfl_xor(s, o, 64);
    if ((tid & 63) == 0) sred[tid >> 6] = s;
    __syncthreads();
    if (tid == 0) {
        float S1 = (sred[0] + sred[1]) + (sred[2] + sred[3]);
        float conf = 1.0f / S1;

        const float third = (float)(1.0 / 3.0);
        const float twoth = (float)(2.0 / 3.0);
        bool b0 = (third > conf) && (0.0f <= conf);
        bool b1 = (twoth > conf) && (third <= conf);
        bool b2 = (1.0f > conf) && (twoth <= conf);
        int idx = b0 ? 0 : (b1 ? 1 : (b2 ? 2 : 0));
        float bl = (idx == 0) ? 0.0f : ((idx == 1) ? third : twoth);
        float nb = (idx == 0) ? 0.8f : ((idx == 1) ? (float)0.86666666666 : (float)0.93333333333);
        float nc = nb + (float)(1.0 / 15.0) * ((conf - bl) / (float)0.2666666667);

        wm[r] = m;
        wnc[r] = nc;
        wminj[r] = NT;   // re-init every launch (re-poison safe)
    }
}

// ---------------------------------------------------------------------------
// Kernel B: full temperature sweep. Grid (NT/32, NB); block = 4 waves;
// each wave evaluates 8 consecutive temps of one row.
// S(t) = sum_c exp2((l_c - m) * LOG2E / t); per element: fma + exp2 + add.
// In-band (row,j) does atomicMin(minj[row], j): min over ok-set == first ok,
// exactly the reference argmax(ok) semantics.
// ---------------------------------------------------------------------------
__global__ __launch_bounds__(256) void sweep_kernel(const float* __restrict__ logits,
                                                    const float* __restrict__ wm,
                                                    const float* __restrict__ wnc,
                                                    int* __restrict__ wminj) {
    int r = blockIdx.y;
    int tid = threadIdx.x;
    int wave = tid >> 6;
    int lane = tid & 63;
    int j0 = blockIdx.x * 32 + wave * 8;

    float m = wm[r];
    float nc = wnc[r];

    float a[8], b[8], s[8];
#pragma unroll
    for (int k = 0; k < 8; ++k) {
        float t = 1.0f - 0.00125f * (float)(j0 + k);   // same expr as reference temps
        a[k] = LOG2E / t;
        b[k] = -(m * a[k]);
        s[k] = 0.f;
    }

    const float4* row4 = (const float4*)(logits + r * NC);
    for (int i = lane; i < NC4; i += 64) {
        float4 v = row4[i];
#pragma unroll
        for (int k = 0; k < 8; ++k) {
            s[k] += exp2f(fmaf(v.x, a[k], b[k]));
            s[k] += exp2f(fmaf(v.y, a[k], b[k]));
            s[k] += exp2f(fmaf(v.z, a[k], b[k]));
            s[k] += exp2f(fmaf(v.w, a[k], b[k]));
        }
    }

#pragma unroll
    for (int k = 0; k < 8; ++k)
        for (int o = 32; o > 0; o >>= 1) s[k] += __shfl_xor(s[k], o, 64);

    if (lane == 0) {
#pragma unroll
        for (int k = 0; k < 8; ++k) {
            // same finishing math as the passing kernel: conft = exp(-log(S))
            float conft = expf(-logf(s[k]));
            if (fabsf(conft - nc) <= 0.01f) atomicMin(&wminj[r], j0 + k);
        }
    }
}

// ---------------------------------------------------------------------------
// Kernel C: write output. 128 blocks x 256 threads, float4 I/O.
// ---------------------------------------------------------------------------
__global__ __launch_bounds__(256) void write_kernel(const float* __restrict__ logits,
                                                    const int* __restrict__ wminj,
                                                    float* __restrict__ out) {
    int r = blockIdx.x;
    int tid = threadIdx.x;
    int mj = wminj[r];
    bool found = mj < NT;
    float tch = found ? (1.0f - 0.00125f * (float)mj) : 1.0f;

    const float4* row4 = (const float4*)(logits + r * NC);
    float4* orow4 = (float4*)(out + r * NC);
    if (tid < NC4) {
        float4 v = row4[tid];
        float4 o;
        o.x = found ? v.x / tch : v.x;   // IEEE div, matches logits/chosen_temp
        o.y = found ? v.y / tch : v.y;
        o.z = found ? v.z / tch : v.z;
        o.w = found ? v.w / tch : v.w;
        orow4[tid] = o;
    }
}

extern "C" void kernel_launch(void* const* d_in, const int* in_sizes, int n_in,
                              void* d_out, int out_size, void* d_ws, size_t ws_size,
                              hipStream_t stream) {
    const float* logits = (const float*)d_in[0];
    float* out = (float*)d_out;

    float* wm = (float*)d_ws;
    float* wnc = wm + NB;
    int* wminj = (int*)(wnc + NB);

    prep_kernel<<<NB, 256, 0, stream>>>(logits, wm, wnc, wminj);
    sweep_kernel<<<dim3(NT / 32, NB), 256, 0, stream>>>(logits, wm, wnc, wminj);
    write_kernel<<<NB, 256, 0, stream>>>(logits, wminj, out);
}

// Round 2
// 61.829 us; speedup vs baseline: 1.4022x; 1.4022x over previous
//
#include <hip/hip_runtime.h>
#include <math.h>

#define NB 128
#define NC 1000
#define NC4 250          // NC/4 float4s per row
#define NT 800
#define NW 16            // waves per block
#define THREADS 1024
#define LOG2E 1.4426950408889634f

// Each wave sums its slice of the row (float4 indices i = w, w+NW, ...) for the
// lane's own temperature params (a,b). All 64 lanes read the SAME LDS address
// per iteration -> broadcast, conflict-free.
__device__ __forceinline__ float probe_sum(const float4* __restrict__ srow4, int w,
                                           float a, float b) {
    float s = 0.f;
#pragma unroll 4
    for (int i = w; i < NC4; i += NW) {
        float4 v = srow4[i];
        s += exp2f(fmaf(v.x, a, b));
        s += exp2f(fmaf(v.y, a, b));
        s += exp2f(fmaf(v.z, a, b));
        s += exp2f(fmaf(v.w, a, b));
    }
    return s;
}

__global__ __launch_bounds__(THREADS) void logitcomp_kernel(const float* __restrict__ logits,
                                                            float* __restrict__ out) {
    __shared__ float4 srow4[NC4];          // staged row (4000 B)
    __shared__ float part[NW][64];         // per-wave partial S per probe
    __shared__ float wred[NW];             // max reduction
    __shared__ float wred2[NW];            // S1 reduction

    const int tid = threadIdx.x;
    const int w = tid >> 6;
    const int lane = tid & 63;
    const int r = blockIdx.x;
    const float4* row4 = (const float4*)(logits + r * NC);

    // ---- stage row + row max ----
    float4 v0 = make_float4(0.f, 0.f, 0.f, 0.f);
    float mv = -INFINITY;
    if (tid < NC4) {
        v0 = row4[tid];
        srow4[tid] = v0;
        mv = fmaxf(fmaxf(v0.x, v0.y), fmaxf(v0.z, v0.w));
    }
    for (int o = 32; o > 0; o >>= 1) mv = fmaxf(mv, __shfl_xor(mv, o, 64));
    if (lane == 0) wred[w] = mv;
    __syncthreads();                       // srow4 + wred visible
    float m = wred[0];
#pragma unroll
    for (int k = 1; k < NW; ++k) m = fmaxf(m, wred[k]);

    // ---- S1 at t=1 (l/1.0f == l, m/1.0f == m exactly), conf, nc ----
    float s1 = 0.f;
    if (tid < NC4) s1 = expf(v0.x - m) + expf(v0.y - m) + expf(v0.z - m) + expf(v0.w - m);
    for (int o = 32; o > 0; o >>= 1) s1 += __shfl_xor(s1, o, 64);
    if (lane == 0) wred2[w] = s1;
    __syncthreads();
    float S1 = 0.f;
#pragma unroll
    for (int k = 0; k < NW; ++k) S1 += wred2[k];
    float conf = 1.0f / S1;

    const float third = (float)(1.0 / 3.0);
    const float twoth = (float)(2.0 / 3.0);
    bool b0 = (third > conf) && (0.0f <= conf);
    bool b1 = (twoth > conf) && (third <= conf);
    bool b2 = (1.0f > conf) && (twoth <= conf);
    int idx = b0 ? 0 : (b1 ? 1 : (b2 ? 2 : 0));
    float bl = (idx == 0) ? 0.0f : ((idx == 1) ? third : twoth);
    float nb = (idx == 0) ? 0.8f : ((idx == 1) ? (float)0.86666666666 : (float)0.93333333333);
    float nc = nb + (float)(1.0 / 15.0) * ((conf - bl) / (float)0.2666666667);

    // ---- round 1: 64 probes at stride 13 covering [0, 799] ----
    // conft(j) is monotone increasing in j (t decreases). below(j) uses the
    // exact reference band predicate so boundaries stay bit-consistent.
    int j1 = min(13 * lane, NT - 1);
    float t1 = 1.0f - 0.00125f * (float)j1;
    float a1 = LOG2E / t1;
    float b1c = -(m * a1);
    float sA = probe_sum(srow4, w, a1, b1c);
    part[w][lane] = sA;
    __syncthreads();
    float SA = 0.f;
#pragma unroll
    for (int k = 0; k < NW; ++k) SA += part[k][lane];   // identical order in every wave
    float cA = expf(-logf(SA));
    bool okA = fabsf(cA - nc) <= 0.01f;
    bool belowA = (cA < nc) && !okA;
    unsigned long long nbm = __ballot(!belowA);         // identical in all waves

    int lo = 0;
    if (nbm != 0ull) {
        int pstar = (int)__ffsll(nbm) - 1;              // first probe not below band
        lo = (pstar == 0) ? 0 : (13 * (pstar - 1) + 1); // window (j_{p*-1}, j_{p*}], width <= 13
    }

    // ---- round 2: stride-1 probes in the window (run unconditionally; block-uniform) ----
    __syncthreads();                                    // WAR on part[]
    int j2 = min(lo + lane, NT - 1);
    float t2 = 1.0f - 0.00125f * (float)j2;
    float a2 = LOG2E / t2;
    float b2c = -(m * a2);
    float sB = probe_sum(srow4, w, a2, b2c);
    part[w][lane] = sB;
    __syncthreads();
    float SB = 0.f;
#pragma unroll
    for (int k = 0; k < NW; ++k) SB += part[k][lane];
    float cB = expf(-logf(SB));
    bool okB = fabsf(cB - nc) <= 0.01f;
    bool belowB = (cB < nc) && !okB;
    unsigned long long nbm2 = __ballot(!belowB);
    unsigned long long okm2 = __ballot(okB);

    bool found = false;
    float tch = 1.0f;
    if (nbm != 0ull && nbm2 != 0ull) {
        int q = (int)__ffsll(nbm2) - 1;                 // first not-below == first candidate
        int jstar = min(lo + q, NT - 1);
        found = ((okm2 >> q) & 1ull) != 0ull;           // reference membership at jstar
        tch = 1.0f - 0.00125f * (float)jstar;
    }

    // ---- write output (IEEE div matches logits / chosen_temp) ----
    float4* orow4 = (float4*)(out + r * NC);
    if (tid < NC4) {
        float4 v = srow4[tid];
        float4 o;
        o.x = found ? v.x / tch : v.x;
        o.y = found ? v.y / tch : v.y;
        o.z = found ? v.z / tch : v.z;
        o.w = found ? v.w / tch : v.w;
        orow4[tid] = o;
    }
}

extern "C" void kernel_launch(void* const* d_in, const int* in_sizes, int n_in,
                              void* d_out, int out_size, void* d_ws, size_t ws_size,
                              hipStream_t stream) {
    const float* logits = (const float*)d_in[0];
    float* out = (float*)d_out;
    logitcomp_kernel<<<NB, THREADS, 0, stream>>>(logits, out);
}

// Round 3
// 57.401 us; speedup vs baseline: 1.5104x; 1.0771x over previous
//
#include <hip/hip_runtime.h>
#include <math.h>

#define NB 128
#define NC 1000
#define NC4 250          // NC/4 float4s per row
#define NT 800
#define NW 16            // waves per block
#define THREADS 1024
#define LOG2E 1.4426950408889634f

// Raw v_exp_f32. Bit-identical to OCML exp2f for x >= -126 (OCML's non-DAZ
// path only differs for subnormal-producing inputs; our args are >= ~-20).
__device__ __forceinline__ float fexp2(float x) { return __builtin_amdgcn_exp2f(x); }

// Round A: lane-parallel probes. Wave w sums its channel slice (i = w, w+NW, ...)
// for the lane's own temp params (a,b). All 64 lanes read the SAME LDS address
// per iteration -> broadcast, conflict-free.
__device__ __forceinline__ float probe_sum_sliced(const float4* __restrict__ srow4, int w,
                                                  float a, float b) {
    float s = 0.f;
#pragma unroll 4
    for (int i = w; i < NC4; i += NW) {
        float4 v = srow4[i];
        s += fexp2(fmaf(v.x, a, b));
        s += fexp2(fmaf(v.y, a, b));
        s += fexp2(fmaf(v.z, a, b));
        s += fexp2(fmaf(v.w, a, b));
    }
    return s;
}

__global__ __launch_bounds__(THREADS) void logitcomp_kernel(const float* __restrict__ logits,
                                                            float* __restrict__ out) {
    __shared__ float4 srow4[NC4];          // staged row (4000 B)
    __shared__ float part[NW][64];         // per-wave partial S per probe (round A)
    __shared__ float wred[NW];             // max reduction
    __shared__ float wred2[NW];            // S1 reduction
    __shared__ int okf[NW];                // round B: ok flags per probe
    __shared__ int blf[NW];                // round B: below flags per probe

    const int tid = threadIdx.x;
    const int w = tid >> 6;
    const int lane = tid & 63;
    const int r = blockIdx.x;
    const float4* row4 = (const float4*)(logits + r * NC);

    // ---- stage row + row max ----
    float4 v0 = make_float4(0.f, 0.f, 0.f, 0.f);
    float mv = -INFINITY;
    if (tid < NC4) {
        v0 = row4[tid];
        srow4[tid] = v0;
        mv = fmaxf(fmaxf(v0.x, v0.y), fmaxf(v0.z, v0.w));
    }
    for (int o = 32; o > 0; o >>= 1) mv = fmaxf(mv, __shfl_xor(mv, o, 64));
    if (lane == 0) wred[w] = mv;
    __syncthreads();                       // srow4 + wred visible
    float m = wred[0];
#pragma unroll
    for (int k = 1; k < NW; ++k) m = fmaxf(m, wred[k]);

    // ---- S1 at t=1 (exact: l/1.0f == l, m/1.0f == m), conf, nc ----
    // Kept bit-identical to the validated kernel (precise expf).
    float s1 = 0.f;
    if (tid < NC4) s1 = expf(v0.x - m) + expf(v0.y - m) + expf(v0.z - m) + expf(v0.w - m);
    for (int o = 32; o > 0; o >>= 1) s1 += __shfl_xor(s1, o, 64);
    if (lane == 0) wred2[w] = s1;
    __syncthreads();
    float S1 = 0.f;
#pragma unroll
    for (int k = 0; k < NW; ++k) S1 += wred2[k];
    float conf = 1.0f / S1;

    const float third = (float)(1.0 / 3.0);
    const float twoth = (float)(2.0 / 3.0);
    bool b0 = (third > conf) && (0.0f <= conf);
    bool b1 = (twoth > conf) && (third <= conf);
    bool b2 = (1.0f > conf) && (twoth <= conf);
    int idx = b0 ? 0 : (b1 ? 1 : (b2 ? 2 : 0));
    float bl = (idx == 0) ? 0.0f : ((idx == 1) ? third : twoth);
    float nb = (idx == 0) ? 0.8f : ((idx == 1) ? (float)0.86666666666 : (float)0.93333333333);
    float nc = nb + (float)(1.0 / 15.0) * ((conf - bl) / (float)0.2666666667);

    // ---- round A: 64 probes at stride 13 covering [0, 799] ----
    // conft(j) is monotone increasing in j. below(j) reuses the exact reference
    // band predicate so boundaries stay bit-consistent.
    int j1 = min(13 * lane, NT - 1);
    float t1 = 1.0f - 0.00125f * (float)j1;
    float a1 = LOG2E / t1;
    float b1c = -(m * a1);
    float sA = probe_sum_sliced(srow4, w, a1, b1c);
    part[w][lane] = sA;
    __syncthreads();
    float SA = 0.f;
#pragma unroll
    for (int k = 0; k < NW; ++k) SA += part[k][lane];   // identical order in every wave
    float cA = expf(-logf(SA));
    bool okA = fabsf(cA - nc) <= 0.01f;
    bool belowA = (cA < nc) && !okA;
    unsigned long long nbm = __ballot(!belowA);         // identical in all waves

    int lo = 0;
    if (nbm != 0ull) {
        int pstar = (int)__ffsll(nbm) - 1;              // first probe not below band
        lo = (pstar == 0) ? 0 : (13 * (pstar - 1) + 1); // window (j_{p*-1}, j_{p*}], width <= 13
    }

    // ---- round B: wave-parallel. Wave w probes j = lo + w; lanes split channels ----
    {
        int j2 = min(lo + w, NT - 1);
        float t2 = 1.0f - 0.00125f * (float)j2;
        float a2 = LOG2E / t2;
        float b2c = -(m * a2);
        float s = 0.f;
        for (int i = lane; i < NC4; i += 64) {
            float4 v = srow4[i];
            s += fexp2(fmaf(v.x, a2, b2c));
            s += fexp2(fmaf(v.y, a2, b2c));
            s += fexp2(fmaf(v.z, a2, b2c));
            s += fexp2(fmaf(v.w, a2, b2c));
        }
        for (int o = 32; o > 0; o >>= 1) s += __shfl_xor(s, o, 64);
        if (lane == 0) {
            float cB = expf(-logf(s));                  // same finisher as validated kernel
            bool okB = fabsf(cB - nc) <= 0.01f;
            bool belowB = (cB < nc) && !okB;
            okf[w] = okB ? 1 : 0;
            blf[w] = belowB ? 1 : 0;
        }
    }
    __syncthreads();

    // ---- pick first not-below probe in window; verify membership there ----
    bool found = false;
    float tch = 1.0f;
    if (nbm != 0ull) {
        int q = -1;
#pragma unroll
        for (int k = NW - 1; k >= 0; --k)
            if (!blf[k]) q = k;                         // lowest w that is not below
        if (q >= 0) {
            int jstar = min(lo + q, NT - 1);
            found = okf[q] != 0;                        // reference membership at jstar
            tch = 1.0f - 0.00125f * (float)jstar;
        }
    }

    // ---- write output (IEEE div matches logits / chosen_temp) ----
    float4* orow4 = (float4*)(out + r * NC);
    if (tid < NC4) {
        float4 v = srow4[tid];
        float4 o;
        o.x = found ? v.x / tch : v.x;
        o.y = found ? v.y / tch : v.y;
        o.z = found ? v.z / tch : v.z;
        o.w = found ? v.w / tch : v.w;
        orow4[tid] = o;
    }
}

extern "C" void kernel_launch(void* const* d_in, const int* in_sizes, int n_in,
                              void* d_out, int out_size, void* d_ws, size_t ws_size,
                              hipStream_t stream) {
    const float* logits = (const float*)d_in[0];
    float* out = (float*)d_out;
    logitcomp_kernel<<<NB, THREADS, 0, stream>>>(logits, out);
}

// Round 4
// 57.326 us; speedup vs baseline: 1.5124x; 1.0013x over previous
//
#include <hip/hip_runtime.h>
#include <math.h>

#define NB 128
#define NC 1000
#define NC4 250          // NC/4 float4s per row
#define NT 800
#define NW 16            // waves per block
#define THREADS 1024
#define LOG2E 1.4426950408889634f

// Raw v_exp_f32. Bit-identical to OCML exp2f for x >= -126; our args >= ~-20.
__device__ __forceinline__ float fexp2(float x) { return __builtin_amdgcn_exp2f(x); }

__global__ __launch_bounds__(THREADS) void logitcomp_kernel(const float* __restrict__ logits,
                                                            float* __restrict__ out) {
    __shared__ float4 srow4[NC4];          // staged row (4000 B)
    __shared__ float wredm[NW];            // max partials
    __shared__ float wred1[NW];            // S1 partials
    __shared__ float part[NW][64];         // round-A per-wave partials per probe
    __shared__ int okf[NW];                // round-B ok flags
    __shared__ int blf[NW];                // round-B below flags

    const int tid = threadIdx.x;
    const int w = tid >> 6;
    const int lane = tid & 63;
    const int r = blockIdx.x;
    const float4* row4 = (const float4*)(logits + r * NC);

    // ---- phase 1: stage row + row max ----
    float4 v0 = make_float4(0.f, 0.f, 0.f, 0.f);
    float mv = -INFINITY;
    if (tid < NC4) {
        v0 = row4[tid];
        srow4[tid] = v0;
        mv = fmaxf(fmaxf(v0.x, v0.y), fmaxf(v0.z, v0.w));
    }
    for (int o = 32; o > 0; o >>= 1) mv = fmaxf(mv, __shfl_xor(mv, o, 64));
    if (lane == 0) wredm[w] = mv;
    __syncthreads();                       // srow4 + wredm visible

    // ---- phase 2: S1 partials (register-only inputs) + round-A probe sums ----
    float m = wredm[0];
#pragma unroll
    for (int k = 1; k < NW; ++k) m = fmaxf(m, wredm[k]);

    // S1 at t=1 — identical math/order to the validated kernel (precise expf).
    float s1 = 0.f;
    if (tid < NC4) s1 = expf(v0.x - m) + expf(v0.y - m) + expf(v0.z - m) + expf(v0.w - m);
    for (int o = 32; o > 0; o >>= 1) s1 += __shfl_xor(s1, o, 64);
    if (lane == 0) wred1[w] = s1;

    // round A: 64 probes at stride 13 covering [0,799]; wave w sums its channel
    // slice (i = w, w+NW, ...) for the lane's own temp. Same-address LDS reads
    // across the wave -> broadcast, conflict-free.
    int j1 = min(13 * lane, NT - 1);
    float t1 = 1.0f - 0.00125f * (float)j1;
    float a1 = LOG2E / t1;
    float b1c = -(m * a1);
    float sA = 0.f;
#pragma unroll 4
    for (int i = w; i < NC4; i += NW) {
        float4 v = srow4[i];
        sA += fexp2(fmaf(v.x, a1, b1c));
        sA += fexp2(fmaf(v.y, a1, b1c));
        sA += fexp2(fmaf(v.z, a1, b1c));
        sA += fexp2(fmaf(v.w, a1, b1c));
    }
    part[w][lane] = sA;
    __syncthreads();                       // wred1 + part visible

    // ---- phase 3: conf/nc, round-A decision, round-B probes (no extra barrier) ----
    float S1 = 0.f;
#pragma unroll
    for (int k = 0; k < NW; ++k) S1 += wred1[k];       // fixed order, all threads
    float conf = 1.0f / S1;

    const float third = (float)(1.0 / 3.0);
    const float twoth = (float)(2.0 / 3.0);
    bool b0 = (third > conf) && (0.0f <= conf);
    bool b1 = (twoth > conf) && (third <= conf);
    bool b2 = (1.0f > conf) && (twoth <= conf);
    int idx = b0 ? 0 : (b1 ? 1 : (b2 ? 2 : 0));
    float bl = (idx == 0) ? 0.0f : ((idx == 1) ? third : twoth);
    float nb = (idx == 0) ? 0.8f : ((idx == 1) ? (float)0.86666666666 : (float)0.93333333333);
    float nc = nb + (float)(1.0 / 15.0) * ((conf - bl) / (float)0.2666666667);

    float SA = 0.f;
#pragma unroll
    for (int k = 0; k < NW; ++k) SA += part[k][lane];  // identical order in every wave
    float cA = expf(-logf(SA));
    bool okA = fabsf(cA - nc) <= 0.01f;
    bool belowA = (cA < nc) && !okA;
    unsigned long long nbm = __ballot(!belowA);        // identical across waves

    int lo = 0;
    if (nbm != 0ull) {
        int pstar = (int)__ffsll(nbm) - 1;             // first probe not below band
        lo = (pstar == 0) ? 0 : (13 * (pstar - 1) + 1);// window (j_{p*-1}, j_{p*}], width <= 13
    }

    // round B: wave w probes j = lo + w (uniform per wave); lanes split channels.
    {
        int j2 = min(lo + w, NT - 1);
        float t2 = 1.0f - 0.00125f * (float)j2;
        float a2 = LOG2E / t2;
        float b2c = -(m * a2);
        float s = 0.f;
        for (int i = lane; i < NC4; i += 64) {
            float4 v = srow4[i];
            s += fexp2(fmaf(v.x, a2, b2c));
            s += fexp2(fmaf(v.y, a2, b2c));
            s += fexp2(fmaf(v.z, a2, b2c));
            s += fexp2(fmaf(v.w, a2, b2c));
        }
        for (int o = 32; o > 0; o >>= 1) s += __shfl_xor(s, o, 64);
        if (lane == 0) {
            float cB = expf(-logf(s));                 // validated finisher
            bool okB = fabsf(cB - nc) <= 0.01f;
            bool belowB = (cB < nc) && !okB;
            okf[w] = okB ? 1 : 0;
            blf[w] = belowB ? 1 : 0;
        }
    }
    __syncthreads();                       // okf + blf visible

    // ---- phase 4: pick first not-below probe; write output from registers ----
    bool found = false;
    float tch = 1.0f;
    if (nbm != 0ull) {
        int q = -1;
#pragma unroll
        for (int k = NW - 1; k >= 0; --k)
            if (!blf[k]) q = k;                        // lowest wave not below band
        if (q >= 0) {
            int jstar = min(lo + q, NT - 1);
            found = okf[q] != 0;                       // reference membership at jstar
            tch = 1.0f - 0.00125f * (float)jstar;
        }
    }

    if (tid < NC4) {
        float4 o;                                      // v0 still live in registers
        o.x = found ? v0.x / tch : v0.x;               // IEEE div matches reference
        o.y = found ? v0.y / tch : v0.y;
        o.z = found ? v0.z / tch : v0.z;
        o.w = found ? v0.w / tch : v0.w;
        ((float4*)(out + r * NC))[tid] = o;
    }
}

extern "C" void kernel_launch(void* const* d_in, const int* in_sizes, int n_in,
                              void* d_out, int out_size, void* d_ws, size_t ws_size,
                              hipStream_t stream) {
    const float* logits = (const float*)d_in[0];
    float* out = (float*)d_out;
    logitcomp_kernel<<<NB, THREADS, 0, stream>>>(logits, out);
}